// Round 3
// baseline (317.701 us; speedup 1.0000x reference)
//
#include <hip/hip_runtime.h>
#include <hip/hip_bf16.h>
#include <math.h>

typedef __bf16 bf16;
typedef __bf16 bf16x4 __attribute__((ext_vector_type(4)));
typedef __bf16 bf16x8 __attribute__((ext_vector_type(8)));
typedef float floatx4 __attribute__((ext_vector_type(4)));
typedef short short4v __attribute__((ext_vector_type(4)));

#define S_LEN 4096
#define DM 1024
#define NH 16
#define HD 64

#define GM 4096
#define GN 1024
#define GK 1024

// async global->LDS, 16B per lane; lds base wave-uniform (m97/m104)
#define GLDS16(gp, lp) __builtin_amdgcn_global_load_lds( \
    (const __attribute__((address_space(1))) void*)(gp), \
    (__attribute__((address_space(3))) void*)(lp), 16, 0, 0)

// ---------------------------------------------------------------------------
// fp32 -> bf16: x (4M) + wq/wk/wv/wo (1M each) into contiguous ws.
// ---------------------------------------------------------------------------
__global__ void cvt_bf16(const float* __restrict__ x,  const float* __restrict__ wq,
                         const float* __restrict__ wk, const float* __restrict__ wv,
                         const float* __restrict__ wo, bf16* __restrict__ dst)
{
    size_t i4 = ((size_t)blockIdx.x * 256 + threadIdx.x) * 4;   // 8M elems total
    const float* src; size_t off;
    const size_t M1 = (size_t)1 << 20;
    if      (i4 < 4 * M1) { src = x;  off = i4;          }
    else if (i4 < 5 * M1) { src = wq; off = i4 - 4 * M1; }
    else if (i4 < 6 * M1) { src = wk; off = i4 - 5 * M1; }
    else if (i4 < 7 * M1) { src = wv; off = i4 - 6 * M1; }
    else                  { src = wo; off = i4 - 7 * M1; }
    float4 v = *(const float4*)(src + off);
    bf16x4 o = { (bf16)v.x, (bf16)v.y, (bf16)v.z, (bf16)v.w };
    *(bf16x4*)(&dst[i4]) = o;
}

// ---------------------------------------------------------------------------
// Fused QKV GEMM, r14: 128x128 tile (m97 structure), 4 waves in 2x2, each
// wave owns 64x64 (4x4 fragments). MFMA:ds_read density 32:16 per k-step
// vs 16:12 of the old 64x128 tile; B re-read traffic halves (GM/BM 64->32).
// C = x*W^T. Epilogue per z:
//   z=0/1 (Q/K): RoPE in-register (pair via shfl_xor(1)) -> Qw/Kw bf16.
//   z=2   (V):   transposed store -> VTw[d_global][s] (packed bf16x4).
// ---------------------------------------------------------------------------
__launch_bounds__(256)
__global__ void gemm_qkv(const bf16* __restrict__ A,
                         const bf16* __restrict__ B0, const bf16* __restrict__ B1,
                         const bf16* __restrict__ B2,
                         const float* __restrict__ cosp, const float* __restrict__ sinp,
                         bf16* __restrict__ Qw, bf16* __restrict__ Kw,
                         bf16* __restrict__ VTw)
{
    const int bz = blockIdx.z;
    const bf16* __restrict__ B = (bz == 0) ? B0 : (bz == 1 ? B1 : B2);

    const int tid  = threadIdx.x;
    const int wave = tid >> 6;
    const int lane = tid & 63;
    const int wm   = (wave >> 1) * 64;
    const int wn   = (wave & 1) * 64;
    const int lrow = lane >> 4;
    const int lcol = lane & 15;

    const int m0 = blockIdx.y * 128;
    const int n0 = blockIdx.x * 128;

    __shared__ __align__(16) bf16 As[128 * 64];
    __shared__ __align__(16) bf16 Bs[128 * 64];

    floatx4 acc[4][4];
    #pragma unroll
    for (int i = 0; i < 4; i++)
        #pragma unroll
        for (int j = 0; j < 4; j++) acc[i][j] = (floatx4){0.f, 0.f, 0.f, 0.f};

    // staging: instr i covers rows i*32 + wave*8 + (lane>>3); lds base wave-uniform
    const bf16* ga0 = A + (size_t)(m0 + wave * 8 + (lane >> 3)) * GK + (lane & 7) * 8;
    const bf16* gb0 = B + (size_t)(n0 + wave * 8 + (lane >> 3)) * GK + (lane & 7) * 8;
    bf16* la = &As[(wave * 8) * 64];
    bf16* lb = &Bs[(wave * 8) * 64];

    for (int kt = 0; kt < GK; kt += 64) {
        #pragma unroll
        for (int i = 0; i < 4; i++) {
            GLDS16(ga0 + kt + (size_t)(i * 32) * GK, la + i * 32 * 64);
            GLDS16(gb0 + kt + (size_t)(i * 32) * GK, lb + i * 32 * 64);
        }
        __syncthreads();
        #pragma unroll
        for (int ks = 0; ks < 2; ks++) {
            bf16x8 af[4], bfr[4];
            #pragma unroll
            for (int t = 0; t < 4; t++)
                af[t]  = *(const bf16x8*)(&As[(wm + t * 16 + lcol) * 64 + ks * 32 + lrow * 8]);
            #pragma unroll
            for (int t = 0; t < 4; t++)
                bfr[t] = *(const bf16x8*)(&Bs[(wn + t * 16 + lcol) * 64 + ks * 32 + lrow * 8]);
            #pragma unroll
            for (int mt = 0; mt < 4; mt++)
                #pragma unroll
                for (int nt = 0; nt < 4; nt++)
                    acc[mt][nt] = __builtin_amdgcn_mfma_f32_16x16x32_bf16(af[mt], bfr[nt], acc[mt][nt], 0, 0, 0);
        }
        __syncthreads();
    }

    if (bz < 2) {
        bf16* __restrict__ C = bz ? Kw : Qw;
        const bool odd = (lcol & 1);
        #pragma unroll
        for (int mt = 0; mt < 4; mt++)
            #pragma unroll
            for (int nt = 0; nt < 4; nt++) {
                int i = (nt * 16 + lcol) >> 1;   // freq index 0..31 (cols repeat per head)
                #pragma unroll
                for (int r = 0; r < 4; r++) {
                    float v  = acc[mt][nt][r];
                    float pv = __shfl_xor(v, 1, 64);
                    int s = m0 + wm + mt * 16 + lrow * 4 + r;
                    float c  = cosp[s * 32 + i];
                    float sn = sinp[s * 32 + i];
                    float ov = odd ? (pv * sn + v * c) : (v * c - pv * sn);
                    C[(size_t)s * GN + n0 + wn + nt * 16 + lcol] = (bf16)ov;
                }
            }
    } else {
        #pragma unroll
        for (int mt = 0; mt < 4; mt++)
            #pragma unroll
            for (int nt = 0; nt < 4; nt++) {
                int col = n0 + wn + nt * 16 + lcol;
                int s   = m0 + wm + mt * 16 + lrow * 4;
                bf16x4 ov = { (bf16)acc[mt][nt][0], (bf16)acc[mt][nt][1],
                              (bf16)acc[mt][nt][2], (bf16)acc[mt][nt][3] };
                *(bf16x4*)(&VTw[(size_t)col * S_LEN + s]) = ov;
            }
    }
}

// ---------------------------------------------------------------------------
// Flash attention v8 (r14): back to STEP=2 — r12/r13's 3-way split added
// +90 MB partial/Q/refetch traffic (FETCH 40->89.5, WRITE 33->73 MB) for
// zero occupancy gain (29.4 vs 31.3) => +17us. Keep swizzled 32K LDS,
// vectorized l-accum, setprio (all perf-neutral-to-positive, VGPR 64).
// Swizzle: 16B chunk c at row r lives at c ^ (r&7).
// ---------------------------------------------------------------------------
#define KSW(row, chunk) (((row) << 6) + ((((chunk) ^ ((row) & 7))) << 3))

template<int STEP>
__launch_bounds__(256, 4)
__global__ void flash_attn(const bf16* __restrict__ Q, const bf16* __restrict__ K,
                           const bf16* __restrict__ VT,
                           float* __restrict__ O0, float* __restrict__ O1,
                           float* __restrict__ L0, float* __restrict__ L1)
{
    const int pi   = blockIdx.x / STEP;
    const int p    = blockIdx.x % STEP;
    const int h    = blockIdx.y;
    const int tid  = threadIdx.x;
    const int wave = tid >> 6;
    const int lane = tid & 63;
    const int lrow = lane >> 4;
    const int lcol = lane & 15;
    const int rsw  = lcol & 7;          // (nt*16+lcol)&7 == lcol&7

    const int qtA = pi;
    const int qtB = 63 - pi;

    float* __restrict__ Op = p ? O1 : O0;
    float* __restrict__ Lp = p ? L1 : L0;

    __shared__ __align__(16) bf16 Ks[2][64 * 64];
    __shared__ __align__(16) bf16 Vs[2][64 * 64];

    const float sc2 = 0.125f * 1.44269504088896340736f;

    const int q0A = qtA * 64 + wave * 16;
    const int q0B = qtB * 64 + wave * 16;

    const bf16* qpA = Q + (size_t)(q0A + lcol) * DM + h * HD;
    const bf16* qpB = Q + (size_t)(q0B + lcol) * DM + h * HD;
    bf16x8 qfA[2], qfB[2];
    qfA[0] = *(const bf16x8*)(qpA + 0 + lrow * 8);
    qfA[1] = *(const bf16x8*)(qpA + 32 + lrow * 8);
    qfB[0] = *(const bf16x8*)(qpB + 0 + lrow * 8);
    qfB[1] = *(const bf16x8*)(qpB + 32 + lrow * 8);

    floatx4 lA4 = (floatx4){0.f, 0.f, 0.f, 0.f};
    floatx4 lB4 = (floatx4){0.f, 0.f, 0.f, 0.f};
    floatx4 oaccA[4], oaccB[4];
    #pragma unroll
    for (int nt = 0; nt < 4; nt++) {
        oaccA[nt] = (floatx4){0.f, 0.f, 0.f, 0.f};
        oaccB[nt] = (floatx4){0.f, 0.f, 0.f, 0.f};
    }

    const int  srow = tid >> 3;          // 0..31
    const int  schk = tid & 7;           // 16B chunk 0..7
    const bf16* kp  = K  + (size_t)srow * DM + h * HD + schk * 8;
    const bf16* vp  = VT + (size_t)(h * HD + srow) * S_LEN + schk * 8;
    const int  wof  = KSW(srow, schk);   // (srow+32)&7 == srow&7 -> +32*64 for row2

    {
        size_t ko = (size_t)p * 64 * DM;
        size_t vo = (size_t)p * 64;
        uint4 a = *(const uint4*)(kp + ko);
        uint4 b = *(const uint4*)(kp + ko + (size_t)32 * DM);
        uint4 c = *(const uint4*)(vp + vo);
        uint4 d = *(const uint4*)(vp + vo + (size_t)32 * S_LEN);
        *(uint4*)(&Ks[0][wof])           = a;
        *(uint4*)(&Ks[0][wof + 32 * 64]) = b;
        *(uint4*)(&Vs[0][wof])           = c;
        *(uint4*)(&Vs[0][wof + 32 * 64]) = d;
    }
    __syncthreads();

    uint4 kr0, kr1, vr0, vr1;
    for (int t = p; t <= qtB; t += STEP) {
        const int  cur  = ((t - p) / STEP) & 1;
        const bool more = (t + STEP <= qtB);
        const bool actA = (t <= qtA);

        if (more) {
            size_t ko = (size_t)(t + STEP) * 64 * DM;
            size_t vo = (size_t)(t + STEP) * 64;
            kr0 = *(const uint4*)(kp + ko);
            kr1 = *(const uint4*)(kp + ko + (size_t)32 * DM);
            vr0 = *(const uint4*)(vp + vo);
            vr1 = *(const uint4*)(vp + vo + (size_t)32 * S_LEN);
        }

        short4v pbA[4], pbB[4];
        const bool diagA = (t == qtA);
        const bool diagB = (t == qtB);
        #pragma unroll
        for (int nt = 0; nt < 4; nt++) {
            floatx4 zB = (floatx4){0.f, 0.f, 0.f, 0.f};
            floatx4 zA = (floatx4){0.f, 0.f, 0.f, 0.f};
            __builtin_amdgcn_s_setprio(1);
            #pragma unroll
            for (int ks = 0; ks < 2; ks++) {
                bf16x8 kf = *(const bf16x8*)(&Ks[cur][((nt * 16 + lcol) << 6) +
                                             ((((ks << 2) + lrow) ^ rsw) << 3)]);
                zB = __builtin_amdgcn_mfma_f32_16x16x32_bf16(kf, qfB[ks], zB, 0, 0, 0);
                if (actA)
                    zA = __builtin_amdgcn_mfma_f32_16x16x32_bf16(kf, qfA[ks], zA, 0, 0, 0);
            }
            __builtin_amdgcn_s_setprio(0);
            if (diagB) {
                #pragma unroll
                for (int r = 0; r < 4; r++) {
                    int kg = t * 64 + nt * 16 + lrow * 4 + r;
                    float pr = exp2f(zB[r] * sc2);
                    if (kg > q0B + lcol) pr = 0.f;
                    zB[r] = pr; lB4[r] += pr;
                }
            } else {
                #pragma unroll
                for (int r = 0; r < 4; r++) {
                    float pr = exp2f(zB[r] * sc2);
                    zB[r] = pr; lB4[r] += pr;
                }
            }
            bf16x4 pvB = { (bf16)zB[0], (bf16)zB[1], (bf16)zB[2], (bf16)zB[3] };
            pbB[nt] = __builtin_bit_cast(short4v, pvB);
            if (actA) {
                if (diagA) {
                    #pragma unroll
                    for (int r = 0; r < 4; r++) {
                        int kg = t * 64 + nt * 16 + lrow * 4 + r;
                        float pr = exp2f(zA[r] * sc2);
                        if (kg > q0A + lcol) pr = 0.f;
                        zA[r] = pr; lA4[r] += pr;
                    }
                } else {
                    #pragma unroll
                    for (int r = 0; r < 4; r++) {
                        float pr = exp2f(zA[r] * sc2);
                        zA[r] = pr; lA4[r] += pr;
                    }
                }
                bf16x4 pvA = { (bf16)zA[0], (bf16)zA[1], (bf16)zA[2], (bf16)zA[3] };
                pbA[nt] = __builtin_bit_cast(short4v, pvA);
            }
        }

        __builtin_amdgcn_s_setprio(1);
        #pragma unroll
        for (int nt = 0; nt < 4; nt++)
            #pragma unroll
            for (int kt = 0; kt < 4; kt++) {
                bf16x4 va = *(const bf16x4*)(&Vs[cur][((nt * 16 + lcol) << 6) +
                              ((((kt << 1) + (lrow >> 1)) ^ rsw) << 3) + ((lrow & 1) << 2)]);
                short4v vas = __builtin_bit_cast(short4v, va);
                oaccB[nt] = __builtin_amdgcn_mfma_f32_16x16x16bf16_1k(vas, pbB[kt], oaccB[nt], 0, 0, 0);
                if (actA)
                    oaccA[nt] = __builtin_amdgcn_mfma_f32_16x16x16bf16_1k(vas, pbA[kt], oaccA[nt], 0, 0, 0);
            }
        __builtin_amdgcn_s_setprio(0);

        if (more) {
            int nxt = cur ^ 1;
            *(uint4*)(&Ks[nxt][wof])           = kr0;
            *(uint4*)(&Ks[nxt][wof + 32 * 64]) = kr1;
            *(uint4*)(&Vs[nxt][wof])           = vr0;
            *(uint4*)(&Vs[nxt][wof + 32 * 64]) = vr1;
        }
        __syncthreads();
    }

    float lA = lA4[0] + lA4[1] + lA4[2] + lA4[3];
    float lB = lB4[0] + lB4[1] + lB4[2] + lB4[3];
    lA += __shfl_xor(lA, 16, 64);
    lA += __shfl_xor(lA, 32, 64);
    lB += __shfl_xor(lB, 16, 64);
    lB += __shfl_xor(lB, 32, 64);
    if (lrow == 0) {
        Lp[h * S_LEN + q0A + lcol] = lA;
        Lp[h * S_LEN + q0B + lcol] = lB;
    }
    #pragma unroll
    for (int nt = 0; nt < 4; nt++) {
        *(floatx4*)(&Op[(size_t)(q0A + lcol) * DM + h * HD + nt * 16 + lrow * 4]) = oaccA[nt];
        *(floatx4*)(&Op[(size_t)(q0B + lcol) * DM + h * HD + nt * 16 + lrow * 4]) = oaccB[nt];
    }
}

// ---------------------------------------------------------------------------
// Combine: Aw = (O0 + O1) / (l0 + l1), fp32 -> bf16.
// ---------------------------------------------------------------------------
__global__ void combine2(const float* __restrict__ O0, const float* __restrict__ O1,
                         const float* __restrict__ L0, const float* __restrict__ L1,
                         bf16* __restrict__ Aw)
{
    int i4 = (blockIdx.x * 256 + threadIdx.x) * 4;   // 4M elems
    int q = i4 >> 10;
    int c = i4 & 1023;
    int h = c >> 6;
    float rl = 1.f / (L0[h * S_LEN + q] + L1[h * S_LEN + q]);
    float4 a = *(const float4*)(O0 + i4);
    float4 b = *(const float4*)(O1 + i4);
    bf16x4 o = { (bf16)((a.x + b.x) * rl), (bf16)((a.y + b.y) * rl),
                 (bf16)((a.z + b.z) * rl), (bf16)((a.w + b.w) * rl) };
    *(bf16x4*)(&Aw[i4]) = o;
}

// ---------------------------------------------------------------------------
// Output projection, r14: 128x128 tile (m97 structure), same loop as
// gemm_qkv with plain fp32 store epilogue.
// ---------------------------------------------------------------------------
__launch_bounds__(256)
__global__ void gemm_out(const bf16* __restrict__ A, const bf16* __restrict__ B,
                         float* __restrict__ out)
{
    const int tid  = threadIdx.x;
    const int wave = tid >> 6;
    const int lane = tid & 63;
    const int wm   = (wave >> 1) * 64;
    const int wn   = (wave & 1) * 64;
    const int lrow = lane >> 4;
    const int lcol = lane & 15;

    const int m0 = blockIdx.y * 128;
    const int n0 = blockIdx.x * 128;

    __shared__ __align__(16) bf16 As[128 * 64];
    __shared__ __align__(16) bf16 Bs[128 * 64];

    floatx4 acc[4][4];
    #pragma unroll
    for (int i = 0; i < 4; i++)
        #pragma unroll
        for (int j = 0; j < 4; j++) acc[i][j] = (floatx4){0.f, 0.f, 0.f, 0.f};

    const bf16* ga0 = A + (size_t)(m0 + wave * 8 + (lane >> 3)) * GK + (lane & 7) * 8;
    const bf16* gb0 = B + (size_t)(n0 + wave * 8 + (lane >> 3)) * GK + (lane & 7) * 8;
    bf16* la = &As[(wave * 8) * 64];
    bf16* lb = &Bs[(wave * 8) * 64];

    for (int kt = 0; kt < GK; kt += 64) {
        #pragma unroll
        for (int i = 0; i < 4; i++) {
            GLDS16(ga0 + kt + (size_t)(i * 32) * GK, la + i * 32 * 64);
            GLDS16(gb0 + kt + (size_t)(i * 32) * GK, lb + i * 32 * 64);
        }
        __syncthreads();
        #pragma unroll
        for (int ks = 0; ks < 2; ks++) {
            bf16x8 af[4], bfr[4];
            #pragma unroll
            for (int t = 0; t < 4; t++)
                af[t]  = *(const bf16x8*)(&As[(wm + t * 16 + lcol) * 64 + ks * 32 + lrow * 8]);
            #pragma unroll
            for (int t = 0; t < 4; t++)
                bfr[t] = *(const bf16x8*)(&Bs[(wn + t * 16 + lcol) * 64 + ks * 32 + lrow * 8]);
            #pragma unroll
            for (int mt = 0; mt < 4; mt++)
                #pragma unroll
                for (int nt = 0; nt < 4; nt++)
                    acc[mt][nt] = __builtin_amdgcn_mfma_f32_16x16x32_bf16(af[mt], bfr[nt], acc[mt][nt], 0, 0, 0);
        }
        __syncthreads();
    }

    #pragma unroll
    for (int mt = 0; mt < 4; mt++)
        #pragma unroll
        for (int nt = 0; nt < 4; nt++)
            #pragma unroll
            for (int r = 0; r < 4; r++) {
                int row = m0 + wm + mt * 16 + lrow * 4 + r;
                int col = n0 + wn + nt * 16 + lcol;
                out[(size_t)row * GN + col] = acc[mt][nt][r];
            }
}

// ---------------------------------------------------------------------------
extern "C" void kernel_launch(void* const* d_in, const int* in_sizes, int n_in,
                              void* d_out, int out_size, void* d_ws, size_t ws_size,
                              hipStream_t stream) {
    const float* x    = (const float*)d_in[0];
    const float* cosp = (const float*)d_in[1];
    const float* sinp = (const float*)d_in[2];
    const float* wq   = (const float*)d_in[4];
    const float* wk   = (const float*)d_in[5];
    const float* wv   = (const float*)d_in[6];
    const float* wo   = (const float*)d_in[7];
    float* out = (float*)d_out;

    const size_t SD = (size_t)S_LEN * DM;   // 4M elems
    const size_t DD = (size_t)DM * DM;      // 1M elems
    bf16* xb  = (bf16*)d_ws;                // 4M bf16
    bf16* wqb = xb + SD;
    bf16* wkb = wqb + DD;
    bf16* wvb = wkb + DD;
    bf16* wob = wvb + DD;
    bf16* Qw  = wob + DD;                   // 4M bf16 each
    bf16* Kw  = Qw + SD;
    bf16* VTw = Kw + SD;
    bf16* Aw  = VTw + SD;
    float* O0f = (float*)(Aw + SD);         // 4M fp32 each
    float* O1f = O0f + SD;
    float* L0f = O1f + SD;                  // 64K fp32 each
    float* L1f = L0f + (size_t)S_LEN * NH;

    // 1) fp32 -> bf16 (x + 4 weights)
    cvt_bf16<<<8192, 256, 0, stream>>>(x, wq, wk, wv, wo, xb);
    // 2) QKV projections + RoPE + V-transpose fused (128x128 tiles, 768 blk)
    gemm_qkv<<<dim3(GN / 128, GM / 128, 3), 256, 0, stream>>>(
        xb, wqb, wkb, wvb, cosp, sinp, Qw, Kw, VTw);
    // 3) flash attention (2-way parity-split partials)
    flash_attn<2><<<dim3(64, NH), 256, 0, stream>>>(
        Qw, Kw, VTw, O0f, O1f, L0f, L1f);
    // 4) combine partials -> bf16 Aw
    combine2<<<S_LEN * DM / 1024, 256, 0, stream>>>(O0f, O1f, L0f, L1f, Aw);
    // 5) output projection (128x128 tiles, 256 blk)
    gemm_out<<<dim3(GN / 128, GM / 128), 256, 0, stream>>>(Aw, wob, out);
}

// Round 4
// 295.845 us; speedup vs baseline: 1.0739x; 1.0739x over previous
//
#include <hip/hip_runtime.h>
#include <hip/hip_bf16.h>
#include <math.h>

typedef __bf16 bf16;
typedef __bf16 bf16x4 __attribute__((ext_vector_type(4)));
typedef __bf16 bf16x8 __attribute__((ext_vector_type(8)));
typedef float floatx4 __attribute__((ext_vector_type(4)));
typedef short short4v __attribute__((ext_vector_type(4)));

#define S_LEN 4096
#define DM 1024
#define NH 16
#define HD 64

#define GM 4096
#define GN 1024
#define GK 1024
#define FST 68     // flash LDS row stride (zero measured conflicts; r3 swizzle was not faster)

// async global->LDS, 16B per lane; lds base wave-uniform (m97/m104)
#define GLDS16(gp, lp) __builtin_amdgcn_global_load_lds( \
    (const __attribute__((address_space(1))) void*)(gp), \
    (__attribute__((address_space(3))) void*)(lp), 16, 0, 0)

// ---------------------------------------------------------------------------
// fp32 -> bf16: x (4M) + wq/wk/wv/wo (1M each) into contiguous ws.
// ---------------------------------------------------------------------------
__global__ void cvt_bf16(const float* __restrict__ x,  const float* __restrict__ wq,
                         const float* __restrict__ wk, const float* __restrict__ wv,
                         const float* __restrict__ wo, bf16* __restrict__ dst)
{
    size_t i4 = ((size_t)blockIdx.x * 256 + threadIdx.x) * 4;   // 8M elems total
    const float* src; size_t off;
    const size_t M1 = (size_t)1 << 20;
    if      (i4 < 4 * M1) { src = x;  off = i4;          }
    else if (i4 < 5 * M1) { src = wq; off = i4 - 4 * M1; }
    else if (i4 < 6 * M1) { src = wk; off = i4 - 5 * M1; }
    else if (i4 < 7 * M1) { src = wv; off = i4 - 6 * M1; }
    else                  { src = wo; off = i4 - 7 * M1; }
    float4 v = *(const float4*)(src + off);
    bf16x4 o = { (bf16)v.x, (bf16)v.y, (bf16)v.z, (bf16)v.w };
    *(bf16x4*)(&dst[i4]) = o;
}

// ---------------------------------------------------------------------------
// Fused QKV GEMM, 64x128 tiles (r11 config, measured-best: 6 blocks/CU).
// C = x*W^T. Epilogue per z:
//   z=0/1 (Q/K): RoPE in-register (pair via shfl_xor(1)) -> Qw/Kw bf16.
//   z=2   (V):   transposed store -> VTw[d_global][s] (packed bf16x4).
// ---------------------------------------------------------------------------
__launch_bounds__(256)
__global__ void gemm_qkv(const bf16* __restrict__ A,
                         const bf16* __restrict__ B0, const bf16* __restrict__ B1,
                         const bf16* __restrict__ B2,
                         const float* __restrict__ cosp, const float* __restrict__ sinp,
                         bf16* __restrict__ Qw, bf16* __restrict__ Kw,
                         bf16* __restrict__ VTw)
{
    const int bz = blockIdx.z;
    const bf16* __restrict__ B = (bz == 0) ? B0 : (bz == 1 ? B1 : B2);

    const int tid  = threadIdx.x;
    const int wave = tid >> 6;
    const int lane = tid & 63;
    const int wm   = (wave >> 1) * 32;
    const int wn   = (wave & 1) * 64;
    const int lrow = lane >> 4;
    const int lcol = lane & 15;

    const int m0 = blockIdx.y * 64;
    const int n0 = blockIdx.x * 128;

    __shared__ __align__(16) bf16 As[64 * 64];
    __shared__ __align__(16) bf16 Bs[128 * 64];

    floatx4 acc[2][4];
    #pragma unroll
    for (int i = 0; i < 2; i++)
        #pragma unroll
        for (int j = 0; j < 4; j++) acc[i][j] = (floatx4){0.f, 0.f, 0.f, 0.f};

    // wave w stages A rows [w*16,+16) (2 instrs), B rows [w*32,+32) (4 instrs)
    const bf16* ga0 = A + (size_t)(m0 + wave * 16 + (lane >> 3)) * GK + (lane & 7) * 8;
    const bf16* gb0 = B + (size_t)(n0 + wave * 32 + (lane >> 3)) * GK + (lane & 7) * 8;
    bf16* la = &As[(wave * 16) * 64];
    bf16* lb = &Bs[(wave * 32) * 64];

    for (int kt = 0; kt < GK; kt += 64) {
        #pragma unroll
        for (int i = 0; i < 2; i++)
            GLDS16(ga0 + kt + (size_t)i * 8 * GK, la + i * 8 * 64);
        #pragma unroll
        for (int i = 0; i < 4; i++)
            GLDS16(gb0 + kt + (size_t)i * 8 * GK, lb + i * 8 * 64);
        __syncthreads();
        #pragma unroll
        for (int ks = 0; ks < 2; ks++) {
            bf16x8 af[2], bfr[4];
            #pragma unroll
            for (int t = 0; t < 2; t++)
                af[t]  = *(const bf16x8*)(&As[(wm + t * 16 + lcol) * 64 + ks * 32 + lrow * 8]);
            #pragma unroll
            for (int t = 0; t < 4; t++)
                bfr[t] = *(const bf16x8*)(&Bs[(wn + t * 16 + lcol) * 64 + ks * 32 + lrow * 8]);
            #pragma unroll
            for (int mt = 0; mt < 2; mt++)
                #pragma unroll
                for (int nt = 0; nt < 4; nt++)
                    acc[mt][nt] = __builtin_amdgcn_mfma_f32_16x16x32_bf16(af[mt], bfr[nt], acc[mt][nt], 0, 0, 0);
        }
        __syncthreads();
    }

    if (bz < 2) {
        bf16* __restrict__ C = bz ? Kw : Qw;
        const bool odd = (lcol & 1);
        #pragma unroll
        for (int mt = 0; mt < 2; mt++)
            #pragma unroll
            for (int nt = 0; nt < 4; nt++) {
                int i = (nt * 16 + lcol) >> 1;   // freq index 0..31 (cols repeat per head)
                #pragma unroll
                for (int r = 0; r < 4; r++) {
                    float v  = acc[mt][nt][r];
                    float pv = __shfl_xor(v, 1, 64);
                    int s = m0 + wm + mt * 16 + lrow * 4 + r;
                    float c  = cosp[s * 32 + i];
                    float sn = sinp[s * 32 + i];
                    float ov = odd ? (pv * sn + v * c) : (v * c - pv * sn);
                    C[(size_t)s * GN + n0 + wn + nt * 16 + lcol] = (bf16)ov;
                }
            }
    } else {
        #pragma unroll
        for (int mt = 0; mt < 2; mt++)
            #pragma unroll
            for (int nt = 0; nt < 4; nt++) {
                int col = n0 + wn + nt * 16 + lcol;
                int s   = m0 + wm + mt * 16 + lrow * 4;
                bf16x4 ov = { (bf16)acc[mt][nt][0], (bf16)acc[mt][nt][1],
                              (bf16)acc[mt][nt][2], (bf16)acc[mt][nt][3] };
                *(bf16x4*)(&VTw[(size_t)col * S_LEN + s]) = ov;
            }
    }
}

// ---------------------------------------------------------------------------
// Flash attention v5 (r0-exact restore: FST=68 pad, scalar l, no setprio —
// the r12 bundle measured +18% slower at identical traffic/conflicts).
// Parity-split + shared-K dual-q.
// ---------------------------------------------------------------------------
__launch_bounds__(256, 4)
__global__ void flash_attn(const bf16* __restrict__ Q, const bf16* __restrict__ K,
                           const bf16* __restrict__ VT,
                           float* __restrict__ O0, float* __restrict__ O1,
                           float* __restrict__ L0, float* __restrict__ L1)
{
    const int pi   = blockIdx.x >> 1;
    const int p    = blockIdx.x & 1;
    const int h    = blockIdx.y;
    const int tid  = threadIdx.x;
    const int wave = tid >> 6;
    const int lane = tid & 63;
    const int lrow = lane >> 4;
    const int lcol = lane & 15;

    const int qtA = pi;
    const int qtB = 63 - pi;

    float* __restrict__ Op = p ? O1 : O0;
    float* __restrict__ Lp = p ? L1 : L0;

    __shared__ __align__(16) bf16 Ks[2][64 * FST];
    __shared__ __align__(16) bf16 Vs[2][64 * FST];

    const float sc2 = 0.125f * 1.44269504088896340736f;

    const int q0A = qtA * 64 + wave * 16;
    const int q0B = qtB * 64 + wave * 16;

    const bf16* qpA = Q + (size_t)(q0A + lcol) * DM + h * HD;
    const bf16* qpB = Q + (size_t)(q0B + lcol) * DM + h * HD;
    bf16x8 qfA[2], qfB[2];
    qfA[0] = *(const bf16x8*)(qpA + 0 + lrow * 8);
    qfA[1] = *(const bf16x8*)(qpA + 32 + lrow * 8);
    qfB[0] = *(const bf16x8*)(qpB + 0 + lrow * 8);
    qfB[1] = *(const bf16x8*)(qpB + 32 + lrow * 8);

    float lA = 0.f, lB = 0.f;
    floatx4 oaccA[4], oaccB[4];
    #pragma unroll
    for (int nt = 0; nt < 4; nt++) {
        oaccA[nt] = (floatx4){0.f, 0.f, 0.f, 0.f};
        oaccB[nt] = (floatx4){0.f, 0.f, 0.f, 0.f};
    }

    const int  srow = tid >> 3;
    const int  sch  = (tid & 7) * 8;
    const bf16* kp  = K  + (size_t)srow * DM + h * HD + sch;
    const bf16* vp  = VT + (size_t)(h * HD + srow) * S_LEN + sch;
    const int  wof  = srow * FST + sch;

    {
        size_t ko = (size_t)p * 64 * DM;
        size_t vo = (size_t)p * 64;
        uint4 a = *(const uint4*)(kp + ko);
        uint4 b = *(const uint4*)(kp + ko + (size_t)32 * DM);
        uint4 c = *(const uint4*)(vp + vo);
        uint4 d = *(const uint4*)(vp + vo + (size_t)32 * S_LEN);
        *(uint4*)(&Ks[0][wof])            = a;
        *(uint4*)(&Ks[0][wof + 32 * FST]) = b;
        *(uint4*)(&Vs[0][wof])            = c;
        *(uint4*)(&Vs[0][wof + 32 * FST]) = d;
    }
    __syncthreads();

    uint4 kr0, kr1, vr0, vr1;
    for (int t = p; t <= qtB; t += 2) {
        const int  cur  = ((t - p) >> 1) & 1;
        const bool more = (t + 2 <= qtB);
        const bool actA = (t <= qtA);

        if (more) {
            size_t ko = (size_t)(t + 2) * 64 * DM;
            size_t vo = (size_t)(t + 2) * 64;
            kr0 = *(const uint4*)(kp + ko);
            kr1 = *(const uint4*)(kp + ko + (size_t)32 * DM);
            vr0 = *(const uint4*)(vp + vo);
            vr1 = *(const uint4*)(vp + vo + (size_t)32 * S_LEN);
        }

        short4v pbA[4], pbB[4];
        const bool diagA = (t == qtA);
        const bool diagB = (t == qtB);
        #pragma unroll
        for (int nt = 0; nt < 4; nt++) {
            floatx4 zB = (floatx4){0.f, 0.f, 0.f, 0.f};
            floatx4 zA = (floatx4){0.f, 0.f, 0.f, 0.f};
            #pragma unroll
            for (int ks = 0; ks < 2; ks++) {
                bf16x8 kf = *(const bf16x8*)(&Ks[cur][(nt * 16 + lcol) * FST + ks * 32 + lrow * 8]);
                zB = __builtin_amdgcn_mfma_f32_16x16x32_bf16(kf, qfB[ks], zB, 0, 0, 0);
                if (actA)
                    zA = __builtin_amdgcn_mfma_f32_16x16x32_bf16(kf, qfA[ks], zA, 0, 0, 0);
            }
            if (diagB) {
                #pragma unroll
                for (int r = 0; r < 4; r++) {
                    int kg = t * 64 + nt * 16 + lrow * 4 + r;
                    float pr = exp2f(zB[r] * sc2);
                    if (kg > q0B + lcol) pr = 0.f;
                    zB[r] = pr; lB += pr;
                }
            } else {
                #pragma unroll
                for (int r = 0; r < 4; r++) {
                    float pr = exp2f(zB[r] * sc2);
                    zB[r] = pr; lB += pr;
                }
            }
            bf16x4 pvB = { (bf16)zB[0], (bf16)zB[1], (bf16)zB[2], (bf16)zB[3] };
            pbB[nt] = __builtin_bit_cast(short4v, pvB);
            if (actA) {
                if (diagA) {
                    #pragma unroll
                    for (int r = 0; r < 4; r++) {
                        int kg = t * 64 + nt * 16 + lrow * 4 + r;
                        float pr = exp2f(zA[r] * sc2);
                        if (kg > q0A + lcol) pr = 0.f;
                        zA[r] = pr; lA += pr;
                    }
                } else {
                    #pragma unroll
                    for (int r = 0; r < 4; r++) {
                        float pr = exp2f(zA[r] * sc2);
                        zA[r] = pr; lA += pr;
                    }
                }
                bf16x4 pvA = { (bf16)zA[0], (bf16)zA[1], (bf16)zA[2], (bf16)zA[3] };
                pbA[nt] = __builtin_bit_cast(short4v, pvA);
            }
        }

        #pragma unroll
        for (int nt = 0; nt < 4; nt++)
            #pragma unroll
            for (int kt = 0; kt < 4; kt++) {
                bf16x4 va = *(const bf16x4*)(&Vs[cur][(nt * 16 + lcol) * FST + kt * 16 + lrow * 4]);
                short4v vas = __builtin_bit_cast(short4v, va);
                oaccB[nt] = __builtin_amdgcn_mfma_f32_16x16x16bf16_1k(vas, pbB[kt], oaccB[nt], 0, 0, 0);
                if (actA)
                    oaccA[nt] = __builtin_amdgcn_mfma_f32_16x16x16bf16_1k(vas, pbA[kt], oaccA[nt], 0, 0, 0);
            }

        if (more) {
            int nxt = cur ^ 1;
            *(uint4*)(&Ks[nxt][wof])            = kr0;
            *(uint4*)(&Ks[nxt][wof + 32 * FST]) = kr1;
            *(uint4*)(&Vs[nxt][wof])            = vr0;
            *(uint4*)(&Vs[nxt][wof + 32 * FST]) = vr1;
        }
        __syncthreads();
    }

    lA += __shfl_xor(lA, 16, 64);
    lA += __shfl_xor(lA, 32, 64);
    lB += __shfl_xor(lB, 16, 64);
    lB += __shfl_xor(lB, 32, 64);
    if (lrow == 0) {
        Lp[h * S_LEN + q0A + lcol] = lA;
        Lp[h * S_LEN + q0B + lcol] = lB;
    }
    #pragma unroll
    for (int nt = 0; nt < 4; nt++) {
        *(floatx4*)(&Op[(size_t)(q0A + lcol) * DM + h * HD + nt * 16 + lrow * 4]) = oaccA[nt];
        *(floatx4*)(&Op[(size_t)(q0B + lcol) * DM + h * HD + nt * 16 + lrow * 4]) = oaccB[nt];
    }
}

// ---------------------------------------------------------------------------
// Combine: Aw = (O0 + O1) / (l0 + l1), fp32 -> bf16.
// ---------------------------------------------------------------------------
__global__ void combine_kernel(const float* __restrict__ O0, const float* __restrict__ O1,
                               const float* __restrict__ L0, const float* __restrict__ L1,
                               bf16* __restrict__ Aw)
{
    int i4 = (blockIdx.x * 256 + threadIdx.x) * 4;   // 4M elems
    int q = i4 >> 10;
    int c = i4 & 1023;
    int h = c >> 6;
    float rl = 1.f / (L0[h * S_LEN + q] + L1[h * S_LEN + q]);
    float4 a = *(const float4*)(O0 + i4);
    float4 b = *(const float4*)(O1 + i4);
    bf16x4 o = { (bf16)((a.x + b.x) * rl), (bf16)((a.y + b.y) * rl),
                 (bf16)((a.z + b.z) * rl), (bf16)((a.w + b.w) * rl) };
    *(bf16x4*)(&Aw[i4]) = o;
}

// ---------------------------------------------------------------------------
// Output projection, r15: 64x128 tiles + SPLIT-K=2. r0's gemm_out had grid
// (8,64)=512 blocks = 2 blocks/CU — the weakest residency in the pipeline.
// blockIdx.z selects K-half; fp32 partials into P0/P1 (reused O0f/O1f);
// tiny addk pass sums them. Doubles resident blocks to 4/CU at identical
// MFMA:ds_read:stage density (16:6:6).
// ---------------------------------------------------------------------------
__launch_bounds__(256)
__global__ void gemm_out_spk(const bf16* __restrict__ A, const bf16* __restrict__ B,
                             float* __restrict__ P0, float* __restrict__ P1)
{
    const int kz   = blockIdx.z;
    float* __restrict__ P = kz ? P1 : P0;

    const int tid  = threadIdx.x;
    const int wave = tid >> 6;
    const int lane = tid & 63;
    const int wm   = (wave >> 1) * 32;
    const int wn   = (wave & 1) * 64;
    const int lrow = lane >> 4;
    const int lcol = lane & 15;

    const int m0 = blockIdx.y * 64;
    const int n0 = blockIdx.x * 128;
    const int k0 = kz * (GK / 2);

    __shared__ __align__(16) bf16 As[64 * 64];
    __shared__ __align__(16) bf16 Bs[128 * 64];

    floatx4 acc[2][4];
    #pragma unroll
    for (int i = 0; i < 2; i++)
        #pragma unroll
        for (int j = 0; j < 4; j++) acc[i][j] = (floatx4){0.f, 0.f, 0.f, 0.f};

    const bf16* ga0 = A + (size_t)(m0 + wave * 16 + (lane >> 3)) * GK + k0 + (lane & 7) * 8;
    const bf16* gb0 = B + (size_t)(n0 + wave * 32 + (lane >> 3)) * GK + k0 + (lane & 7) * 8;
    bf16* la = &As[(wave * 16) * 64];
    bf16* lb = &Bs[(wave * 32) * 64];

    for (int kt = 0; kt < GK / 2; kt += 64) {
        #pragma unroll
        for (int i = 0; i < 2; i++)
            GLDS16(ga0 + kt + (size_t)i * 8 * GK, la + i * 8 * 64);
        #pragma unroll
        for (int i = 0; i < 4; i++)
            GLDS16(gb0 + kt + (size_t)i * 8 * GK, lb + i * 8 * 64);
        __syncthreads();
        #pragma unroll
        for (int ks = 0; ks < 2; ks++) {
            bf16x8 af[2], bfr[4];
            #pragma unroll
            for (int t = 0; t < 2; t++)
                af[t]  = *(const bf16x8*)(&As[(wm + t * 16 + lcol) * 64 + ks * 32 + lrow * 8]);
            #pragma unroll
            for (int t = 0; t < 4; t++)
                bfr[t] = *(const bf16x8*)(&Bs[(wn + t * 16 + lcol) * 64 + ks * 32 + lrow * 8]);
            #pragma unroll
            for (int mt = 0; mt < 2; mt++)
                #pragma unroll
                for (int nt = 0; nt < 4; nt++)
                    acc[mt][nt] = __builtin_amdgcn_mfma_f32_16x16x32_bf16(af[mt], bfr[nt], acc[mt][nt], 0, 0, 0);
        }
        __syncthreads();
    }

    #pragma unroll
    for (int mt = 0; mt < 2; mt++)
        #pragma unroll
        for (int nt = 0; nt < 4; nt++)
            #pragma unroll
            for (int r = 0; r < 4; r++) {
                int row = m0 + wm + mt * 16 + lrow * 4 + r;
                int col = n0 + wn + nt * 16 + lcol;
                P[(size_t)row * GN + col] = acc[mt][nt][r];
            }
}

__global__ void addk(const float* __restrict__ P0, const float* __restrict__ P1,
                     float* __restrict__ out)
{
    int i4 = (blockIdx.x * 256 + threadIdx.x) * 4;   // 4M elems
    float4 a = *(const float4*)(P0 + i4);
    float4 b = *(const float4*)(P1 + i4);
    float4 o = { a.x + b.x, a.y + b.y, a.z + b.z, a.w + b.w };
    *(float4*)(out + i4) = o;
}

// ---------------------------------------------------------------------------
extern "C" void kernel_launch(void* const* d_in, const int* in_sizes, int n_in,
                              void* d_out, int out_size, void* d_ws, size_t ws_size,
                              hipStream_t stream) {
    const float* x    = (const float*)d_in[0];
    const float* cosp = (const float*)d_in[1];
    const float* sinp = (const float*)d_in[2];
    const float* wq   = (const float*)d_in[4];
    const float* wk   = (const float*)d_in[5];
    const float* wv   = (const float*)d_in[6];
    const float* wo   = (const float*)d_in[7];
    float* out = (float*)d_out;

    const size_t SD = (size_t)S_LEN * DM;   // 4M elems
    const size_t DD = (size_t)DM * DM;      // 1M elems
    bf16* xb  = (bf16*)d_ws;                // 4M bf16
    bf16* wqb = xb + SD;
    bf16* wkb = wqb + DD;
    bf16* wvb = wkb + DD;
    bf16* wob = wvb + DD;
    bf16* Qw  = wob + DD;                   // 4M bf16 each
    bf16* Kw  = Qw + SD;
    bf16* VTw = Kw + SD;
    bf16* Aw  = VTw + SD;
    float* O0f = (float*)(Aw + SD);         // 4M fp32 each
    float* O1f = O0f + SD;
    float* L0f = O1f + SD;                  // 64K fp32 each
    float* L1f = L0f + (size_t)S_LEN * NH;

    // 1) fp32 -> bf16 (x + 4 weights)
    cvt_bf16<<<8192, 256, 0, stream>>>(x, wq, wk, wv, wo, xb);
    // 2) QKV projections + RoPE + V-transpose fused (64x128 tiles, 6 blk/CU)
    gemm_qkv<<<dim3(GN / 128, GM / 64, 3), 256, 0, stream>>>(
        xb, wqb, wkb, wvb, cosp, sinp, Qw, Kw, VTw);
    // 3) flash attention (parity-split partials)
    flash_attn<<<dim3(64, NH), 256, 0, stream>>>(Qw, Kw, VTw, O0f, O1f, L0f, L1f);
    // 4) combine partials -> bf16 Aw
    combine_kernel<<<S_LEN * DM / 1024, 256, 0, stream>>>(O0f, O1f, L0f, L1f, Aw);
    // 5) output projection, split-K=2 (partials reuse O0f/O1f — free after combine)
    gemm_out_spk<<<dim3(GN / 128, GM / 64, 2), 256, 0, stream>>>(Aw, wob, O0f, O1f);
    addk<<<S_LEN * DM / 1024, 256, 0, stream>>>(O0f, O1f, out);
}

// Round 6
// 289.080 us; speedup vs baseline: 1.0990x; 1.0234x over previous
//
#include <hip/hip_runtime.h>
#include <hip/hip_bf16.h>
#include <math.h>

typedef __bf16 bf16;
typedef __bf16 bf16x4 __attribute__((ext_vector_type(4)));
typedef __bf16 bf16x8 __attribute__((ext_vector_type(8)));
typedef float floatx4 __attribute__((ext_vector_type(4)));
typedef short short4v __attribute__((ext_vector_type(4)));

#define S_LEN 4096
#define DM 1024
#define NH 16
#define HD 64

#define GM 4096
#define GN 1024
#define GK 1024
#define FST 68     // flash LDS row stride (r0-exact)

// softmax scale folded into Q at projection: 1/sqrt(64) * log2(e)
#define QSCALE 0.18033688011112042f

// async global->LDS, 16B per lane; lds base wave-uniform (m97/m104)
#define GLDS16(gp, lp) __builtin_amdgcn_global_load_lds( \
    (const __attribute__((address_space(1))) void*)(gp), \
    (__attribute__((address_space(3))) void*)(lp), 16, 0, 0)

// ---------------------------------------------------------------------------
// fp32 -> bf16: x (4M) + wq/wk/wv/wo (1M each) into contiguous ws.
// ---------------------------------------------------------------------------
__global__ void cvt_bf16(const float* __restrict__ x,  const float* __restrict__ wq,
                         const float* __restrict__ wk, const float* __restrict__ wv,
                         const float* __restrict__ wo, bf16* __restrict__ dst)
{
    size_t i4 = ((size_t)blockIdx.x * 256 + threadIdx.x) * 4;   // 8M elems total
    const float* src; size_t off;
    const size_t M1 = (size_t)1 << 20;
    if      (i4 < 4 * M1) { src = x;  off = i4;          }
    else if (i4 < 5 * M1) { src = wq; off = i4 - 4 * M1; }
    else if (i4 < 6 * M1) { src = wk; off = i4 - 5 * M1; }
    else if (i4 < 7 * M1) { src = wv; off = i4 - 6 * M1; }
    else                  { src = wo; off = i4 - 7 * M1; }
    float4 v = *(const float4*)(src + off);
    bf16x4 o = { (bf16)v.x, (bf16)v.y, (bf16)v.z, (bf16)v.w };
    *(bf16x4*)(&dst[i4]) = o;
}

// ---------------------------------------------------------------------------
// Fused QKV GEMM r16: 64x128 tile, BK=64, DOUBLE-BUFFERED LDS (48KB, 3/CU).
// Stage(kt+1) issued BEFORE compute(kt), ONE barrier/iter => stage latency
// hidden under compute (T3-minimum; old code staged then immediately
// barriered = full latency exposed every iter).
// T2 XOR swizzle: LDS 16B-chunk p at row r holds logical chunk p^(r&7).
//   write side: pre-swizzled GLOBAL source (GLDS dest must stay linear,
//   rule #21): src chunk = (lane&7)^((lane>>3)&7)  [lane-constant]
//   read side:  offset  = ((ks*4+lrow)^(lcol&7))*8 [lane-constant]
// => each 8-lane ds_read_b128 batch hits all 32 banks (was 4-way conflict).
// Epilogue per z: z=0 Q: RoPE * QSCALE; z=1 K: RoPE; z=2 V: transposed store.
// ---------------------------------------------------------------------------
__launch_bounds__(256)
__global__ void gemm_qkv(const bf16* __restrict__ A,
                         const bf16* __restrict__ B0, const bf16* __restrict__ B1,
                         const bf16* __restrict__ B2,
                         const float* __restrict__ cosp, const float* __restrict__ sinp,
                         bf16* __restrict__ Qw, bf16* __restrict__ Kw,
                         bf16* __restrict__ VTw)
{
    const int bz = blockIdx.z;
    const bf16* __restrict__ B = (bz == 0) ? B0 : (bz == 1 ? B1 : B2);

    const int tid  = threadIdx.x;
    const int wave = tid >> 6;
    const int lane = tid & 63;
    const int wm   = (wave >> 1) * 32;
    const int wn   = (wave & 1) * 64;
    const int lrow = lane >> 4;
    const int lcol = lane & 15;

    const int m0 = blockIdx.y * 64;
    const int n0 = blockIdx.x * 128;

    __shared__ __align__(16) bf16 As[2][64 * 64];
    __shared__ __align__(16) bf16 Bs[2][128 * 64];

    floatx4 acc[2][4];
    #pragma unroll
    for (int i = 0; i < 2; i++)
        #pragma unroll
        for (int j = 0; j < 4; j++) acc[i][j] = (floatx4){0.f, 0.f, 0.f, 0.f};

    // pre-swizzled global source chunk (write side of T2)
    const int swc = (((lane & 7) ^ ((lane >> 3) & 7))) * 8;
    const bf16* ga0 = A + (size_t)(m0 + wave * 16 + (lane >> 3)) * GK + swc;
    const bf16* gb0 = B + (size_t)(n0 + wave * 32 + (lane >> 3)) * GK + swc;
    // swizzled read offsets (read side of T2), lane-constant
    const int kof0 = ((0 + lrow) ^ (lcol & 7)) * 8;
    const int kof1 = ((4 + lrow) ^ (lcol & 7)) * 8;

    // prologue: stage kt=0 -> buf 0
    #pragma unroll
    for (int i = 0; i < 2; i++)
        GLDS16(ga0 + (size_t)i * 8 * GK, &As[0][(wave * 16 + i * 8) * 64]);
    #pragma unroll
    for (int i = 0; i < 4; i++)
        GLDS16(gb0 + (size_t)i * 8 * GK, &Bs[0][(wave * 32 + i * 8) * 64]);
    __syncthreads();

    int cur = 0;
    for (int kt = 0; kt < GK; kt += 64) {
        if (kt + 64 < GK) {   // stage next tile early; latency hides under compute
            #pragma unroll
            for (int i = 0; i < 2; i++)
                GLDS16(ga0 + kt + 64 + (size_t)i * 8 * GK, &As[cur ^ 1][(wave * 16 + i * 8) * 64]);
            #pragma unroll
            for (int i = 0; i < 4; i++)
                GLDS16(gb0 + kt + 64 + (size_t)i * 8 * GK, &Bs[cur ^ 1][(wave * 32 + i * 8) * 64]);
        }
        #pragma unroll
        for (int ks = 0; ks < 2; ks++) {
            const int ko = ks ? kof1 : kof0;
            bf16x8 af[2], bfr[4];
            #pragma unroll
            for (int t = 0; t < 2; t++)
                af[t]  = *(const bf16x8*)(&As[cur][(wm + t * 16 + lcol) * 64 + ko]);
            #pragma unroll
            for (int t = 0; t < 4; t++)
                bfr[t] = *(const bf16x8*)(&Bs[cur][(wn + t * 16 + lcol) * 64 + ko]);
            #pragma unroll
            for (int mt = 0; mt < 2; mt++)
                #pragma unroll
                for (int nt = 0; nt < 4; nt++)
                    acc[mt][nt] = __builtin_amdgcn_mfma_f32_16x16x32_bf16(af[mt], bfr[nt], acc[mt][nt], 0, 0, 0);
        }
        __syncthreads();   // drains stage(kt+64) (covered) + gates buffer swap
        cur ^= 1;
    }

    if (bz < 2) {
        bf16* __restrict__ C = bz ? Kw : Qw;
        const float qs = (bz == 0) ? QSCALE : 1.0f;
        const bool odd = (lcol & 1);
        #pragma unroll
        for (int mt = 0; mt < 2; mt++)
            #pragma unroll
            for (int nt = 0; nt < 4; nt++) {
                int i = (nt * 16 + lcol) >> 1;   // freq index 0..31 (cols repeat per head)
                #pragma unroll
                for (int r = 0; r < 4; r++) {
                    float v  = acc[mt][nt][r];
                    float pv = __shfl_xor(v, 1, 64);
                    int s = m0 + wm + mt * 16 + lrow * 4 + r;
                    float c  = cosp[s * 32 + i];
                    float sn = sinp[s * 32 + i];
                    float ov = odd ? (pv * sn + v * c) : (v * c - pv * sn);
                    C[(size_t)s * GN + n0 + wn + nt * 16 + lcol] = (bf16)(ov * qs);
                }
            }
    } else {
        #pragma unroll
        for (int mt = 0; mt < 2; mt++)
            #pragma unroll
            for (int nt = 0; nt < 4; nt++) {
                int col = n0 + wn + nt * 16 + lcol;
                int s   = m0 + wm + mt * 16 + lrow * 4;
                bf16x4 ov = { (bf16)acc[mt][nt][0], (bf16)acc[mt][nt][1],
                              (bf16)acc[mt][nt][2], (bf16)acc[mt][nt][3] };
                *(bf16x4*)(&VTw[(size_t)col * S_LEN + s]) = ov;
            }
    }
}

// ---------------------------------------------------------------------------
// Flash attention v9 (r16): r0 structure, two VALU cuts (it is VALU-bound:
// VALUBusy 51% vs MfmaUtil 22%):
//   (a) softmax scale pre-folded into Q at projection -> exp2f(z) direct
//       (removes 32 v_mul per tile-iter)
//   (b) l computed on the MFMA pipe: ones-vector x P-fragments, replacing
//       32 scalar adds/iter + the final cross-lane shuffles.
// ---------------------------------------------------------------------------
__launch_bounds__(256, 4)
__global__ void flash_attn(const bf16* __restrict__ Q, const bf16* __restrict__ K,
                           const bf16* __restrict__ VT,
                           float* __restrict__ O0, float* __restrict__ O1,
                           float* __restrict__ L0, float* __restrict__ L1)
{
    const int pi   = blockIdx.x >> 1;
    const int p    = blockIdx.x & 1;
    const int h    = blockIdx.y;
    const int tid  = threadIdx.x;
    const int wave = tid >> 6;
    const int lane = tid & 63;
    const int lrow = lane >> 4;
    const int lcol = lane & 15;

    const int qtA = pi;
    const int qtB = 63 - pi;

    float* __restrict__ Op = p ? O1 : O0;
    float* __restrict__ Lp = p ? L1 : L0;

    __shared__ __align__(16) bf16 Ks[2][64 * FST];
    __shared__ __align__(16) bf16 Vs[2][64 * FST];

    const int q0A = qtA * 64 + wave * 16;
    const int q0B = qtB * 64 + wave * 16;

    const bf16* qpA = Q + (size_t)(q0A + lcol) * DM + h * HD;
    const bf16* qpB = Q + (size_t)(q0B + lcol) * DM + h * HD;
    bf16x8 qfA[2], qfB[2];
    qfA[0] = *(const bf16x8*)(qpA + 0 + lrow * 8);
    qfA[1] = *(const bf16x8*)(qpA + 32 + lrow * 8);
    qfB[0] = *(const bf16x8*)(qpB + 0 + lrow * 8);
    qfB[1] = *(const bf16x8*)(qpB + 32 + lrow * 8);

    const bf16 one_b = (bf16)1.0f;
    const bf16x4 onev = { one_b, one_b, one_b, one_b };
    const short4v ones_s = __builtin_bit_cast(short4v, onev);

    floatx4 laccA = (floatx4){0.f, 0.f, 0.f, 0.f};
    floatx4 laccB = (floatx4){0.f, 0.f, 0.f, 0.f};
    floatx4 oaccA[4], oaccB[4];
    #pragma unroll
    for (int nt = 0; nt < 4; nt++) {
        oaccA[nt] = (floatx4){0.f, 0.f, 0.f, 0.f};
        oaccB[nt] = (floatx4){0.f, 0.f, 0.f, 0.f};
    }

    const int  srow = tid >> 3;
    const int  sch  = (tid & 7) * 8;
    const bf16* kp  = K  + (size_t)srow * DM + h * HD + sch;
    const bf16* vp  = VT + (size_t)(h * HD + srow) * S_LEN + sch;
    const int  wof  = srow * FST + sch;

    {
        size_t ko = (size_t)p * 64 * DM;
        size_t vo = (size_t)p * 64;
        uint4 a = *(const uint4*)(kp + ko);
        uint4 b = *(const uint4*)(kp + ko + (size_t)32 * DM);
        uint4 c = *(const uint4*)(vp + vo);
        uint4 d = *(const uint4*)(vp + vo + (size_t)32 * S_LEN);
        *(uint4*)(&Ks[0][wof])            = a;
        *(uint4*)(&Ks[0][wof + 32 * FST]) = b;
        *(uint4*)(&Vs[0][wof])            = c;
        *(uint4*)(&Vs[0][wof + 32 * FST]) = d;
    }
    __syncthreads();

    uint4 kr0, kr1, vr0, vr1;
    for (int t = p; t <= qtB; t += 2) {
        const int  cur  = ((t - p) >> 1) & 1;
        const bool more = (t + 2 <= qtB);
        const bool actA = (t <= qtA);

        if (more) {
            size_t ko = (size_t)(t + 2) * 64 * DM;
            size_t vo = (size_t)(t + 2) * 64;
            kr0 = *(const uint4*)(kp + ko);
            kr1 = *(const uint4*)(kp + ko + (size_t)32 * DM);
            vr0 = *(const uint4*)(vp + vo);
            vr1 = *(const uint4*)(vp + vo + (size_t)32 * S_LEN);
        }

        short4v pbA[4], pbB[4];
        const bool diagA = (t == qtA);
        const bool diagB = (t == qtB);
        #pragma unroll
        for (int nt = 0; nt < 4; nt++) {
            floatx4 zB = (floatx4){0.f, 0.f, 0.f, 0.f};
            floatx4 zA = (floatx4){0.f, 0.f, 0.f, 0.f};
            #pragma unroll
            for (int ks = 0; ks < 2; ks++) {
                bf16x8 kf = *(const bf16x8*)(&Ks[cur][(nt * 16 + lcol) * FST + ks * 32 + lrow * 8]);
                zB = __builtin_amdgcn_mfma_f32_16x16x32_bf16(kf, qfB[ks], zB, 0, 0, 0);
                if (actA)
                    zA = __builtin_amdgcn_mfma_f32_16x16x32_bf16(kf, qfA[ks], zA, 0, 0, 0);
            }
            if (diagB) {
                #pragma unroll
                for (int r = 0; r < 4; r++) {
                    int kg = t * 64 + nt * 16 + lrow * 4 + r;
                    float pr = exp2f(zB[r]);
                    if (kg > q0B + lcol) pr = 0.f;
                    zB[r] = pr;
                }
            } else {
                #pragma unroll
                for (int r = 0; r < 4; r++)
                    zB[r] = exp2f(zB[r]);
            }
            bf16x4 pvB = { (bf16)zB[0], (bf16)zB[1], (bf16)zB[2], (bf16)zB[3] };
            pbB[nt] = __builtin_bit_cast(short4v, pvB);
            if (actA) {
                if (diagA) {
                    #pragma unroll
                    for (int r = 0; r < 4; r++) {
                        int kg = t * 64 + nt * 16 + lrow * 4 + r;
                        float pr = exp2f(zA[r]);
                        if (kg > q0A + lcol) pr = 0.f;
                        zA[r] = pr;
                    }
                } else {
                    #pragma unroll
                    for (int r = 0; r < 4; r++)
                        zA[r] = exp2f(zA[r]);
                }
                bf16x4 pvA = { (bf16)zA[0], (bf16)zA[1], (bf16)zA[2], (bf16)zA[3] };
                pbA[nt] = __builtin_bit_cast(short4v, pvA);
            }
        }

        // l on the MFMA pipe: D[row][q] = sum_k 1 * P[k][q]  (all rows equal)
        #pragma unroll
        for (int kt = 0; kt < 4; kt++) {
            laccB = __builtin_amdgcn_mfma_f32_16x16x16bf16_1k(ones_s, pbB[kt], laccB, 0, 0, 0);
            if (actA)
                laccA = __builtin_amdgcn_mfma_f32_16x16x16bf16_1k(ones_s, pbA[kt], laccA, 0, 0, 0);
        }

        #pragma unroll
        for (int nt = 0; nt < 4; nt++)
            #pragma unroll
            for (int kt = 0; kt < 4; kt++) {
                bf16x4 va = *(const bf16x4*)(&Vs[cur][(nt * 16 + lcol) * FST + kt * 16 + lrow * 4]);
                short4v vas = __builtin_bit_cast(short4v, va);
                oaccB[nt] = __builtin_amdgcn_mfma_f32_16x16x16bf16_1k(vas, pbB[kt], oaccB[nt], 0, 0, 0);
                if (actA)
                    oaccA[nt] = __builtin_amdgcn_mfma_f32_16x16x16bf16_1k(vas, pbA[kt], oaccA[nt], 0, 0, 0);
            }

        if (more) {
            int nxt = cur ^ 1;
            *(uint4*)(&Ks[nxt][wof])            = kr0;
            *(uint4*)(&Ks[nxt][wof + 32 * FST]) = kr1;
            *(uint4*)(&Vs[nxt][wof])            = vr0;
            *(uint4*)(&Vs[nxt][wof + 32 * FST]) = vr1;
        }
        __syncthreads();
    }

    if (lrow == 0) {
        Lp[h * S_LEN + q0A + lcol] = laccA[0];
        Lp[h * S_LEN + q0B + lcol] = laccB[0];
    }
    #pragma unroll
    for (int nt = 0; nt < 4; nt++) {
        *(floatx4*)(&Op[(size_t)(q0A + lcol) * DM + h * HD + nt * 16 + lrow * 4]) = oaccA[nt];
        *(floatx4*)(&Op[(size_t)(q0B + lcol) * DM + h * HD + nt * 16 + lrow * 4]) = oaccB[nt];
    }
}

// ---------------------------------------------------------------------------
// Combine: Aw = (O0 + O1) / (l0 + l1), fp32 -> bf16.
// ---------------------------------------------------------------------------
__global__ void combine_kernel(const float* __restrict__ O0, const float* __restrict__ O1,
                               const float* __restrict__ L0, const float* __restrict__ L1,
                               bf16* __restrict__ Aw)
{
    int i4 = (blockIdx.x * 256 + threadIdx.x) * 4;   // 4M elems
    int q = i4 >> 10;
    int c = i4 & 1023;
    int h = c >> 6;
    float rl = 1.f / (L0[h * S_LEN + q] + L1[h * S_LEN + q]);
    float4 a = *(const float4*)(O0 + i4);
    float4 b = *(const float4*)(O1 + i4);
    bf16x4 o = { (bf16)((a.x + b.x) * rl), (bf16)((a.y + b.y) * rl),
                 (bf16)((a.z + b.z) * rl), (bf16)((a.w + b.w) * rl) };
    *(bf16x4*)(&Aw[i4]) = o;
}

// ---------------------------------------------------------------------------
// Output projection r16: same dbuf + swizzle structure as gemm_qkv,
// plain fp32 store epilogue. Single dispatch (split-K measured neutral
// on the GEMM and addk cost ~8us => reverted).
// ---------------------------------------------------------------------------
__launch_bounds__(256)
__global__ void gemm_out(const bf16* __restrict__ A, const bf16* __restrict__ B,
                         float* __restrict__ out)
{
    const int tid  = threadIdx.x;
    const int wave = tid >> 6;
    const int lane = tid & 63;
    const int wm   = (wave >> 1) * 32;
    const int wn   = (wave & 1) * 64;
    const int lrow = lane >> 4;
    const int lcol = lane & 15;

    const int m0 = blockIdx.y * 64;
    const int n0 = blockIdx.x * 128;

    __shared__ __align__(16) bf16 As[2][64 * 64];
    __shared__ __align__(16) bf16 Bs[2][128 * 64];

    floatx4 acc[2][4];
    #pragma unroll
    for (int i = 0; i < 2; i++)
        #pragma unroll
        for (int j = 0; j < 4; j++) acc[i][j] = (floatx4){0.f, 0.f, 0.f, 0.f};

    const int swc = (((lane & 7) ^ ((lane >> 3) & 7))) * 8;
    const bf16* ga0 = A + (size_t)(m0 + wave * 16 + (lane >> 3)) * GK + swc;
    const bf16* gb0 = B + (size_t)(n0 + wave * 32 + (lane >> 3)) * GK + swc;
    const int kof0 = ((0 + lrow) ^ (lcol & 7)) * 8;
    const int kof1 = ((4 + lrow) ^ (lcol & 7)) * 8;

    #pragma unroll
    for (int i = 0; i < 2; i++)
        GLDS16(ga0 + (size_t)i * 8 * GK, &As[0][(wave * 16 + i * 8) * 64]);
    #pragma unroll
    for (int i = 0; i < 4; i++)
        GLDS16(gb0 + (size_t)i * 8 * GK, &Bs[0][(wave * 32 + i * 8) * 64]);
    __syncthreads();

    int cur = 0;
    for (int kt = 0; kt < GK; kt += 64) {
        if (kt + 64 < GK) {
            #pragma unroll
            for (int i = 0; i < 2; i++)
                GLDS16(ga0 + kt + 64 + (size_t)i * 8 * GK, &As[cur ^ 1][(wave * 16 + i * 8) * 64]);
            #pragma unroll
            for (int i = 0; i < 4; i++)
                GLDS16(gb0 + kt + 64 + (size_t)i * 8 * GK, &Bs[cur ^ 1][(wave * 32 + i * 8) * 64]);
        }
        #pragma unroll
        for (int ks = 0; ks < 2; ks++) {
            const int ko = ks ? kof1 : kof0;
            bf16x8 af[2], bfr[4];
            #pragma unroll
            for (int t = 0; t < 2; t++)
                af[t]  = *(const bf16x8*)(&As[cur][(wm + t * 16 + lcol) * 64 + ko]);
            #pragma unroll
            for (int t = 0; t < 4; t++)
                bfr[t] = *(const bf16x8*)(&Bs[cur][(wn + t * 16 + lcol) * 64 + ko]);
            #pragma unroll
            for (int mt = 0; mt < 2; mt++)
                #pragma unroll
                for (int nt = 0; nt < 4; nt++)
                    acc[mt][nt] = __builtin_amdgcn_mfma_f32_16x16x32_bf16(af[mt], bfr[nt], acc[mt][nt], 0, 0, 0);
        }
        __syncthreads();
        cur ^= 1;
    }

    #pragma unroll
    for (int mt = 0; mt < 2; mt++)
        #pragma unroll
        for (int nt = 0; nt < 4; nt++)
            #pragma unroll
            for (int r = 0; r < 4; r++) {
                int row = m0 + wm + mt * 16 + lrow * 4 + r;
                int col = n0 + wn + nt * 16 + lcol;
                out[(size_t)row * GN + col] = acc[mt][nt][r];
            }
}

// ---------------------------------------------------------------------------
extern "C" void kernel_launch(void* const* d_in, const int* in_sizes, int n_in,
                              void* d_out, int out_size, void* d_ws, size_t ws_size,
                              hipStream_t stream) {
    const float* x    = (const float*)d_in[0];
    const float* cosp = (const float*)d_in[1];
    const float* sinp = (const float*)d_in[2];
    const float* wq   = (const float*)d_in[4];
    const float* wk   = (const float*)d_in[5];
    const float* wv   = (const float*)d_in[6];
    const float* wo   = (const float*)d_in[7];
    float* out = (float*)d_out;

    const size_t SD = (size_t)S_LEN * DM;   // 4M elems
    const size_t DD = (size_t)DM * DM;      // 1M elems
    bf16* xb  = (bf16*)d_ws;                // 4M bf16
    bf16* wqb = xb + SD;
    bf16* wkb = wqb + DD;
    bf16* wvb = wkb + DD;
    bf16* wob = wvb + DD;
    bf16* Qw  = wob + DD;                   // 4M bf16 each
    bf16* Kw  = Qw + SD;
    bf16* VTw = Kw + SD;
    bf16* Aw  = VTw + SD;
    float* O0f = (float*)(Aw + SD);         // 4M fp32 each
    float* O1f = O0f + SD;
    float* L0f = O1f + SD;                  // 64K fp32 each
    float* L1f = L0f + (size_t)S_LEN * NH;

    // 1) fp32 -> bf16 (x + 4 weights)
    cvt_bf16<<<8192, 256, 0, stream>>>(x, wq, wk, wv, wo, xb);
    // 2) QKV projections + RoPE(+scale) + V-transpose fused (dbuf+swizzle)
    gemm_qkv<<<dim3(GN / 128, GM / 64, 3), 256, 0, stream>>>(
        xb, wqb, wkb, wvb, cosp, sinp, Qw, Kw, VTw);
    // 3) flash attention (parity-split partials)
    flash_attn<<<dim3(64, NH), 256, 0, stream>>>(Qw, Kw, VTw, O0f, O1f, L0f, L1f);
    // 4) combine partials -> bf16 Aw
    combine_kernel<<<S_LEN * DM / 1024, 256, 0, stream>>>(O0f, O1f, L0f, L1f, Aw);
    // 5) output projection (dbuf+swizzle)
    gemm_out<<<dim3(GN / 128, GM / 64), 256, 0, stream>>>(Aw, wob, out);
}

// Round 7
// 284.166 us; speedup vs baseline: 1.1180x; 1.0173x over previous
//
#include <hip/hip_runtime.h>
#include <hip/hip_bf16.h>
#include <math.h>

typedef __bf16 bf16;
typedef __bf16 bf16x4 __attribute__((ext_vector_type(4)));
typedef __bf16 bf16x8 __attribute__((ext_vector_type(8)));
typedef float floatx4 __attribute__((ext_vector_type(4)));
typedef short short4v __attribute__((ext_vector_type(4)));

#define S_LEN 4096
#define DM 1024
#define NH 16
#define HD 64

#define GM 4096
#define GN 1024
#define GK 1024
#define FST 68     // flash LDS row stride (r0-exact, zero measured conflicts)

// softmax scale folded into Q at projection: 1/sqrt(64) * log2(e)
#define QSCALE 0.18033688011112042f

// async global->LDS, 16B per lane; lds base wave-uniform (m97/m104)
#define GLDS16(gp, lp) __builtin_amdgcn_global_load_lds( \
    (const __attribute__((address_space(1))) void*)(gp), \
    (__attribute__((address_space(3))) void*)(lp), 16, 0, 0)

// ---------------------------------------------------------------------------
// fp32 -> bf16: x (4M) + wq/wk/wv/wo (1M each) into contiguous ws.
// ---------------------------------------------------------------------------
__global__ void cvt_bf16(const float* __restrict__ x,  const float* __restrict__ wq,
                         const float* __restrict__ wk, const float* __restrict__ wv,
                         const float* __restrict__ wo, bf16* __restrict__ dst)
{
    size_t i4 = ((size_t)blockIdx.x * 256 + threadIdx.x) * 4;   // 8M elems total
    const float* src; size_t off;
    const size_t M1 = (size_t)1 << 20;
    if      (i4 < 4 * M1) { src = x;  off = i4;          }
    else if (i4 < 5 * M1) { src = wq; off = i4 - 4 * M1; }
    else if (i4 < 6 * M1) { src = wk; off = i4 - 5 * M1; }
    else if (i4 < 7 * M1) { src = wv; off = i4 - 6 * M1; }
    else                  { src = wo; off = i4 - 7 * M1; }
    float4 v = *(const float4*)(src + off);
    bf16x4 o = { (bf16)v.x, (bf16)v.y, (bf16)v.z, (bf16)v.w };
    *(bf16x4*)(&dst[i4]) = o;
}

// ---------------------------------------------------------------------------
// Fused QKV GEMM (r6-kept): 64x128 tile, BK=64, dbuf LDS (48KB, 3/CU),
// T2 XOR swizzle (write via pre-swizzled global src, read via XOR offset).
// Measured: non-flash total -3.6us vs r0 structure (bank-conflict fix; the
// dbuf itself is m99-null since __syncthreads drains the prefetch anyway).
// Epilogue per z: z=0 Q: RoPE * QSCALE; z=1 K: RoPE; z=2 V: transposed store.
// ---------------------------------------------------------------------------
__launch_bounds__(256)
__global__ void gemm_qkv(const bf16* __restrict__ A,
                         const bf16* __restrict__ B0, const bf16* __restrict__ B1,
                         const bf16* __restrict__ B2,
                         const float* __restrict__ cosp, const float* __restrict__ sinp,
                         bf16* __restrict__ Qw, bf16* __restrict__ Kw,
                         bf16* __restrict__ VTw)
{
    const int bz = blockIdx.z;
    const bf16* __restrict__ B = (bz == 0) ? B0 : (bz == 1 ? B1 : B2);

    const int tid  = threadIdx.x;
    const int wave = tid >> 6;
    const int lane = tid & 63;
    const int wm   = (wave >> 1) * 32;
    const int wn   = (wave & 1) * 64;
    const int lrow = lane >> 4;
    const int lcol = lane & 15;

    const int m0 = blockIdx.y * 64;
    const int n0 = blockIdx.x * 128;

    __shared__ __align__(16) bf16 As[2][64 * 64];
    __shared__ __align__(16) bf16 Bs[2][128 * 64];

    floatx4 acc[2][4];
    #pragma unroll
    for (int i = 0; i < 2; i++)
        #pragma unroll
        for (int j = 0; j < 4; j++) acc[i][j] = (floatx4){0.f, 0.f, 0.f, 0.f};

    // pre-swizzled global source chunk (write side of T2)
    const int swc = (((lane & 7) ^ ((lane >> 3) & 7))) * 8;
    const bf16* ga0 = A + (size_t)(m0 + wave * 16 + (lane >> 3)) * GK + swc;
    const bf16* gb0 = B + (size_t)(n0 + wave * 32 + (lane >> 3)) * GK + swc;
    // swizzled read offsets (read side of T2), lane-constant
    const int kof0 = ((0 + lrow) ^ (lcol & 7)) * 8;
    const int kof1 = ((4 + lrow) ^ (lcol & 7)) * 8;

    // prologue: stage kt=0 -> buf 0
    #pragma unroll
    for (int i = 0; i < 2; i++)
        GLDS16(ga0 + (size_t)i * 8 * GK, &As[0][(wave * 16 + i * 8) * 64]);
    #pragma unroll
    for (int i = 0; i < 4; i++)
        GLDS16(gb0 + (size_t)i * 8 * GK, &Bs[0][(wave * 32 + i * 8) * 64]);
    __syncthreads();

    int cur = 0;
    for (int kt = 0; kt < GK; kt += 64) {
        if (kt + 64 < GK) {   // stage next tile early
            #pragma unroll
            for (int i = 0; i < 2; i++)
                GLDS16(ga0 + kt + 64 + (size_t)i * 8 * GK, &As[cur ^ 1][(wave * 16 + i * 8) * 64]);
            #pragma unroll
            for (int i = 0; i < 4; i++)
                GLDS16(gb0 + kt + 64 + (size_t)i * 8 * GK, &Bs[cur ^ 1][(wave * 32 + i * 8) * 64]);
        }
        #pragma unroll
        for (int ks = 0; ks < 2; ks++) {
            const int ko = ks ? kof1 : kof0;
            bf16x8 af[2], bfr[4];
            #pragma unroll
            for (int t = 0; t < 2; t++)
                af[t]  = *(const bf16x8*)(&As[cur][(wm + t * 16 + lcol) * 64 + ko]);
            #pragma unroll
            for (int t = 0; t < 4; t++)
                bfr[t] = *(const bf16x8*)(&Bs[cur][(wn + t * 16 + lcol) * 64 + ko]);
            #pragma unroll
            for (int mt = 0; mt < 2; mt++)
                #pragma unroll
                for (int nt = 0; nt < 4; nt++)
                    acc[mt][nt] = __builtin_amdgcn_mfma_f32_16x16x32_bf16(af[mt], bfr[nt], acc[mt][nt], 0, 0, 0);
        }
        __syncthreads();
        cur ^= 1;
    }

    if (bz < 2) {
        bf16* __restrict__ C = bz ? Kw : Qw;
        const float qs = (bz == 0) ? QSCALE : 1.0f;
        const bool odd = (lcol & 1);
        #pragma unroll
        for (int mt = 0; mt < 2; mt++)
            #pragma unroll
            for (int nt = 0; nt < 4; nt++) {
                int i = (nt * 16 + lcol) >> 1;   // freq index 0..31 (cols repeat per head)
                #pragma unroll
                for (int r = 0; r < 4; r++) {
                    float v  = acc[mt][nt][r];
                    float pv = __shfl_xor(v, 1, 64);
                    int s = m0 + wm + mt * 16 + lrow * 4 + r;
                    float c  = cosp[s * 32 + i];
                    float sn = sinp[s * 32 + i];
                    float ov = odd ? (pv * sn + v * c) : (v * c - pv * sn);
                    C[(size_t)s * GN + n0 + wn + nt * 16 + lcol] = (bf16)(ov * qs);
                }
            }
    } else {
        #pragma unroll
        for (int mt = 0; mt < 2; mt++)
            #pragma unroll
            for (int nt = 0; nt < 4; nt++) {
                int col = n0 + wn + nt * 16 + lcol;
                int s   = m0 + wm + mt * 16 + lrow * 4;
                bf16x4 ov = { (bf16)acc[mt][nt][0], (bf16)acc[mt][nt][1],
                              (bf16)acc[mt][nt][2], (bf16)acc[mt][nt][3] };
                *(bf16x4*)(&VTw[(size_t)col * S_LEN + s]) = ov;
            }
    }
}

// ---------------------------------------------------------------------------
// Flash attention r17: r0-exact loop body (scalar l on the co-issuing VALU
// pipe — r6's l-on-MFMA added +17% MFMA work on the binding pipe, +6.7us).
// Only kept change vs r0: softmax scale pre-folded into Q (exp2f direct).
// ---------------------------------------------------------------------------
__launch_bounds__(256, 4)
__global__ void flash_attn(const bf16* __restrict__ Q, const bf16* __restrict__ K,
                           const bf16* __restrict__ VT,
                           float* __restrict__ O0, float* __restrict__ O1,
                           float* __restrict__ L0, float* __restrict__ L1)
{
    const int pi   = blockIdx.x >> 1;
    const int p    = blockIdx.x & 1;
    const int h    = blockIdx.y;
    const int tid  = threadIdx.x;
    const int wave = tid >> 6;
    const int lane = tid & 63;
    const int lrow = lane >> 4;
    const int lcol = lane & 15;

    const int qtA = pi;
    const int qtB = 63 - pi;

    float* __restrict__ Op = p ? O1 : O0;
    float* __restrict__ Lp = p ? L1 : L0;

    __shared__ __align__(16) bf16 Ks[2][64 * FST];
    __shared__ __align__(16) bf16 Vs[2][64 * FST];

    const int q0A = qtA * 64 + wave * 16;
    const int q0B = qtB * 64 + wave * 16;

    const bf16* qpA = Q + (size_t)(q0A + lcol) * DM + h * HD;
    const bf16* qpB = Q + (size_t)(q0B + lcol) * DM + h * HD;
    bf16x8 qfA[2], qfB[2];
    qfA[0] = *(const bf16x8*)(qpA + 0 + lrow * 8);
    qfA[1] = *(const bf16x8*)(qpA + 32 + lrow * 8);
    qfB[0] = *(const bf16x8*)(qpB + 0 + lrow * 8);
    qfB[1] = *(const bf16x8*)(qpB + 32 + lrow * 8);

    float lA = 0.f, lB = 0.f;
    floatx4 oaccA[4], oaccB[4];
    #pragma unroll
    for (int nt = 0; nt < 4; nt++) {
        oaccA[nt] = (floatx4){0.f, 0.f, 0.f, 0.f};
        oaccB[nt] = (floatx4){0.f, 0.f, 0.f, 0.f};
    }

    const int  srow = tid >> 3;
    const int  sch  = (tid & 7) * 8;
    const bf16* kp  = K  + (size_t)srow * DM + h * HD + sch;
    const bf16* vp  = VT + (size_t)(h * HD + srow) * S_LEN + sch;
    const int  wof  = srow * FST + sch;

    {
        size_t ko = (size_t)p * 64 * DM;
        size_t vo = (size_t)p * 64;
        uint4 a = *(const uint4*)(kp + ko);
        uint4 b = *(const uint4*)(kp + ko + (size_t)32 * DM);
        uint4 c = *(const uint4*)(vp + vo);
        uint4 d = *(const uint4*)(vp + vo + (size_t)32 * S_LEN);
        *(uint4*)(&Ks[0][wof])            = a;
        *(uint4*)(&Ks[0][wof + 32 * FST]) = b;
        *(uint4*)(&Vs[0][wof])            = c;
        *(uint4*)(&Vs[0][wof + 32 * FST]) = d;
    }
    __syncthreads();

    uint4 kr0, kr1, vr0, vr1;
    for (int t = p; t <= qtB; t += 2) {
        const int  cur  = ((t - p) >> 1) & 1;
        const bool more = (t + 2 <= qtB);
        const bool actA = (t <= qtA);

        if (more) {
            size_t ko = (size_t)(t + 2) * 64 * DM;
            size_t vo = (size_t)(t + 2) * 64;
            kr0 = *(const uint4*)(kp + ko);
            kr1 = *(const uint4*)(kp + ko + (size_t)32 * DM);
            vr0 = *(const uint4*)(vp + vo);
            vr1 = *(const uint4*)(vp + vo + (size_t)32 * S_LEN);
        }

        short4v pbA[4], pbB[4];
        const bool diagA = (t == qtA);
        const bool diagB = (t == qtB);
        #pragma unroll
        for (int nt = 0; nt < 4; nt++) {
            floatx4 zB = (floatx4){0.f, 0.f, 0.f, 0.f};
            floatx4 zA = (floatx4){0.f, 0.f, 0.f, 0.f};
            #pragma unroll
            for (int ks = 0; ks < 2; ks++) {
                bf16x8 kf = *(const bf16x8*)(&Ks[cur][(nt * 16 + lcol) * FST + ks * 32 + lrow * 8]);
                zB = __builtin_amdgcn_mfma_f32_16x16x32_bf16(kf, qfB[ks], zB, 0, 0, 0);
                if (actA)
                    zA = __builtin_amdgcn_mfma_f32_16x16x32_bf16(kf, qfA[ks], zA, 0, 0, 0);
            }
            if (diagB) {
                #pragma unroll
                for (int r = 0; r < 4; r++) {
                    int kg = t * 64 + nt * 16 + lrow * 4 + r;
                    float pr = exp2f(zB[r]);
                    if (kg > q0B + lcol) pr = 0.f;
                    zB[r] = pr; lB += pr;
                }
            } else {
                #pragma unroll
                for (int r = 0; r < 4; r++) {
                    float pr = exp2f(zB[r]);
                    zB[r] = pr; lB += pr;
                }
            }
            bf16x4 pvB = { (bf16)zB[0], (bf16)zB[1], (bf16)zB[2], (bf16)zB[3] };
            pbB[nt] = __builtin_bit_cast(short4v, pvB);
            if (actA) {
                if (diagA) {
                    #pragma unroll
                    for (int r = 0; r < 4; r++) {
                        int kg = t * 64 + nt * 16 + lrow * 4 + r;
                        float pr = exp2f(zA[r]);
                        if (kg > q0A + lcol) pr = 0.f;
                        zA[r] = pr; lA += pr;
                    }
                } else {
                    #pragma unroll
                    for (int r = 0; r < 4; r++) {
                        float pr = exp2f(zA[r]);
                        zA[r] = pr; lA += pr;
                    }
                }
                bf16x4 pvA = { (bf16)zA[0], (bf16)zA[1], (bf16)zA[2], (bf16)zA[3] };
                pbA[nt] = __builtin_bit_cast(short4v, pvA);
            }
        }

        #pragma unroll
        for (int nt = 0; nt < 4; nt++)
            #pragma unroll
            for (int kt = 0; kt < 4; kt++) {
                bf16x4 va = *(const bf16x4*)(&Vs[cur][(nt * 16 + lcol) * FST + kt * 16 + lrow * 4]);
                short4v vas = __builtin_bit_cast(short4v, va);
                oaccB[nt] = __builtin_amdgcn_mfma_f32_16x16x16bf16_1k(vas, pbB[kt], oaccB[nt], 0, 0, 0);
                if (actA)
                    oaccA[nt] = __builtin_amdgcn_mfma_f32_16x16x16bf16_1k(vas, pbA[kt], oaccA[nt], 0, 0, 0);
            }

        if (more) {
            int nxt = cur ^ 1;
            *(uint4*)(&Ks[nxt][wof])            = kr0;
            *(uint4*)(&Ks[nxt][wof + 32 * FST]) = kr1;
            *(uint4*)(&Vs[nxt][wof])            = vr0;
            *(uint4*)(&Vs[nxt][wof + 32 * FST]) = vr1;
        }
        __syncthreads();
    }

    lA += __shfl_xor(lA, 16, 64);
    lA += __shfl_xor(lA, 32, 64);
    lB += __shfl_xor(lB, 16, 64);
    lB += __shfl_xor(lB, 32, 64);
    if (lrow == 0) {
        Lp[h * S_LEN + q0A + lcol] = lA;
        Lp[h * S_LEN + q0B + lcol] = lB;
    }
    #pragma unroll
    for (int nt = 0; nt < 4; nt++) {
        *(floatx4*)(&Op[(size_t)(q0A + lcol) * DM + h * HD + nt * 16 + lrow * 4]) = oaccA[nt];
        *(floatx4*)(&Op[(size_t)(q0B + lcol) * DM + h * HD + nt * 16 + lrow * 4]) = oaccB[nt];
    }
}

// ---------------------------------------------------------------------------
// Combine: Aw = (O0 + O1) / (l0 + l1), fp32 -> bf16.
// ---------------------------------------------------------------------------
__global__ void combine_kernel(const float* __restrict__ O0, const float* __restrict__ O1,
                               const float* __restrict__ L0, const float* __restrict__ L1,
                               bf16* __restrict__ Aw)
{
    int i4 = (blockIdx.x * 256 + threadIdx.x) * 4;   // 4M elems
    int q = i4 >> 10;
    int c = i4 & 1023;
    int h = c >> 6;
    float rl = 1.f / (L0[h * S_LEN + q] + L1[h * S_LEN + q]);
    float4 a = *(const float4*)(O0 + i4);
    float4 b = *(const float4*)(O1 + i4);
    bf16x4 o = { (bf16)((a.x + b.x) * rl), (bf16)((a.y + b.y) * rl),
                 (bf16)((a.z + b.z) * rl), (bf16)((a.w + b.w) * rl) };
    *(bf16x4*)(&Aw[i4]) = o;
}

// ---------------------------------------------------------------------------
// Output projection (r6-kept): dbuf + swizzle, fp32 store epilogue.
// ---------------------------------------------------------------------------
__launch_bounds__(256)
__global__ void gemm_out(const bf16* __restrict__ A, const bf16* __restrict__ B,
                         float* __restrict__ out)
{
    const int tid  = threadIdx.x;
    const int wave = tid >> 6;
    const int lane = tid & 63;
    const int wm   = (wave >> 1) * 32;
    const int wn   = (wave & 1) * 64;
    const int lrow = lane >> 4;
    const int lcol = lane & 15;

    const int m0 = blockIdx.y * 64;
    const int n0 = blockIdx.x * 128;

    __shared__ __align__(16) bf16 As[2][64 * 64];
    __shared__ __align__(16) bf16 Bs[2][128 * 64];

    floatx4 acc[2][4];
    #pragma unroll
    for (int i = 0; i < 2; i++)
        #pragma unroll
        for (int j = 0; j < 4; j++) acc[i][j] = (floatx4){0.f, 0.f, 0.f, 0.f};

    const int swc = (((lane & 7) ^ ((lane >> 3) & 7))) * 8;
    const bf16* ga0 = A + (size_t)(m0 + wave * 16 + (lane >> 3)) * GK + swc;
    const bf16* gb0 = B + (size_t)(n0 + wave * 32 + (lane >> 3)) * GK + swc;
    const int kof0 = ((0 + lrow) ^ (lcol & 7)) * 8;
    const int kof1 = ((4 + lrow) ^ (lcol & 7)) * 8;

    #pragma unroll
    for (int i = 0; i < 2; i++)
        GLDS16(ga0 + (size_t)i * 8 * GK, &As[0][(wave * 16 + i * 8) * 64]);
    #pragma unroll
    for (int i = 0; i < 4; i++)
        GLDS16(gb0 + (size_t)i * 8 * GK, &Bs[0][(wave * 32 + i * 8) * 64]);
    __syncthreads();

    int cur = 0;
    for (int kt = 0; kt < GK; kt += 64) {
        if (kt + 64 < GK) {
            #pragma unroll
            for (int i = 0; i < 2; i++)
                GLDS16(ga0 + kt + 64 + (size_t)i * 8 * GK, &As[cur ^ 1][(wave * 16 + i * 8) * 64]);
            #pragma unroll
            for (int i = 0; i < 4; i++)
                GLDS16(gb0 + kt + 64 + (size_t)i * 8 * GK, &Bs[cur ^ 1][(wave * 32 + i * 8) * 64]);
        }
        #pragma unroll
        for (int ks = 0; ks < 2; ks++) {
            const int ko = ks ? kof1 : kof0;
            bf16x8 af[2], bfr[4];
            #pragma unroll
            for (int t = 0; t < 2; t++)
                af[t]  = *(const bf16x8*)(&As[cur][(wm + t * 16 + lcol) * 64 + ko]);
            #pragma unroll
            for (int t = 0; t < 4; t++)
                bfr[t] = *(const bf16x8*)(&Bs[cur][(wn + t * 16 + lcol) * 64 + ko]);
            #pragma unroll
            for (int mt = 0; mt < 2; mt++)
                #pragma unroll
                for (int nt = 0; nt < 4; nt++)
                    acc[mt][nt] = __builtin_amdgcn_mfma_f32_16x16x32_bf16(af[mt], bfr[nt], acc[mt][nt], 0, 0, 0);
        }
        __syncthreads();
        cur ^= 1;
    }

    #pragma unroll
    for (int mt = 0; mt < 2; mt++)
        #pragma unroll
        for (int nt = 0; nt < 4; nt++)
            #pragma unroll
            for (int r = 0; r < 4; r++) {
                int row = m0 + wm + mt * 16 + lrow * 4 + r;
                int col = n0 + wn + nt * 16 + lcol;
                out[(size_t)row * GN + col] = acc[mt][nt][r];
            }
}

// ---------------------------------------------------------------------------
extern "C" void kernel_launch(void* const* d_in, const int* in_sizes, int n_in,
                              void* d_out, int out_size, void* d_ws, size_t ws_size,
                              hipStream_t stream) {
    const float* x    = (const float*)d_in[0];
    const float* cosp = (const float*)d_in[1];
    const float* sinp = (const float*)d_in[2];
    const float* wq   = (const float*)d_in[4];
    const float* wk   = (const float*)d_in[5];
    const float* wv   = (const float*)d_in[6];
    const float* wo   = (const float*)d_in[7];
    float* out = (float*)d_out;

    const size_t SD = (size_t)S_LEN * DM;   // 4M elems
    const size_t DD = (size_t)DM * DM;      // 1M elems
    bf16* xb  = (bf16*)d_ws;                // 4M bf16
    bf16* wqb = xb + SD;
    bf16* wkb = wqb + DD;
    bf16* wvb = wkb + DD;
    bf16* wob = wvb + DD;
    bf16* Qw  = wob + DD;                   // 4M bf16 each
    bf16* Kw  = Qw + SD;
    bf16* VTw = Kw + SD;
    bf16* Aw  = VTw + SD;
    float* O0f = (float*)(Aw + SD);         // 4M fp32 each
    float* O1f = O0f + SD;
    float* L0f = O1f + SD;                  // 64K fp32 each
    float* L1f = L0f + (size_t)S_LEN * NH;

    // 1) fp32 -> bf16 (x + 4 weights)
    cvt_bf16<<<8192, 256, 0, stream>>>(x, wq, wk, wv, wo, xb);
    // 2) QKV projections + RoPE(+scale) + V-transpose fused (dbuf+swizzle)
    gemm_qkv<<<dim3(GN / 128, GM / 64, 3), 256, 0, stream>>>(
        xb, wqb, wkb, wvb, cosp, sinp, Qw, Kw, VTw);
    // 3) flash attention (parity-split partials)
    flash_attn<<<dim3(64, NH), 256, 0, stream>>>(Qw, Kw, VTw, O0f, O1f, L0f, L1f);
    // 4) combine partials -> bf16 Aw
    combine_kernel<<<S_LEN * DM / 1024, 256, 0, stream>>>(O0f, O1f, L0f, L1f, Aw);
    // 5) output projection (dbuf+swizzle)
    gemm_out<<<dim3(GN / 128, GM / 64), 256, 0, stream>>>(Aw, wob, out);
}